// Round 11
// baseline (89.526 us; speedup 1.0000x reference)
//
#include <hip/hip_runtime.h>
#include <stdint.h>

// hipcc defaults to -ffp-contract=fast; FMA fusion perturbs IoU by ~1 ulp vs
// numpy and flips discrete selections (R3-R6 ladder). Force per-op IEEE f32.
#pragma clang fp contract(off)

#define BATCH 32
#define NROI  12000
#define NGT   200
#define BGCLS 20
#define ROIBS 256
#define NPOS  64
#define NBIN  1024
#define CAP   1024
#define TSEL  1024       // k_sel block size
#define VPT2  12         // ceil(NROI/TSEL) values per k_sel thread
#define HSH   16         // histogram shards (lane-based)
#define HST   (NBIN + 2) // shard stride: same bin -> different banks/addresses
#define RPT   2          // rois per thread in k_ioumax
#define IOBLK (256 * RPT)

// Exact reference IoU max/argmax over compacted valid GTs (first-max wins).
// Bit-exact numpy f32: left-to-right ((ar+ag)-inter)+1e-8, IEEE div.
__device__ __forceinline__ void roi_maxiou_all(const float4* cbox, const float* carea,
                                               int nv, float ry1, float rx1,
                                               float ry2, float rx2,
                                               float& best, int& bj) {
#pragma clang fp contract(off)
  float ar = (ry2 - ry1) * (rx2 - rx1);
  best = -1.0f; bj = 0;
  for (int j = 0; j < nv; ++j) {
    float4 q = cbox[j];
    float yy1 = fmaxf(ry1, q.x);
    float xx1 = fmaxf(rx1, q.y);
    float yy2 = fminf(ry2, q.z);
    float xx2 = fminf(rx2, q.w);
    float inter = fmaxf(yy2 - yy1, 0.0f) * fmaxf(xx2 - xx1, 0.0f);
    float den = ((ar + carea[j]) - inter) + 1e-8f;
    float iou = inter / den;
    if (iou > best) { best = iou; bj = j; }      // strict > == first-index argmax
  }
}

// Fast path: approx iou = inter * v_rcp(den) (~2 ulp). Track top-2 approx +
// argmax per roi. If the winner leads by > margin (5e-6 rel, 20x the error
// bound), it is provably the exact f32 argmax -> compute the exact IEEE IoU
// for that single j (bit-exact). Near-ties take the exact full-loop fallback.
// RPT rois per thread: GT load/addressing amortized, 2 independent chains.
__global__ __launch_bounds__(256, 4) void k_ioumax(const float* __restrict__ rois,
                                                   const int* __restrict__ gtc,
                                                   const float* __restrict__ gtb,
                                                   float* __restrict__ max_iou,
                                                   int* __restrict__ best_j) {
#pragma clang fp contract(off)
  __shared__ float4 cbox[NGT];
  __shared__ float carea[NGT];
  __shared__ int snv, wtmp[4];
  const int b = blockIdx.y;
  const int tid = threadIdx.x;

  {                                              // order-preserving compaction
    bool valid = false; float4 p = make_float4(0.f, 0.f, 0.f, 0.f);
    if (tid < NGT) {
      p = *(const float4*)(gtb + ((size_t)b * NGT + tid) * 4);
      valid = gtc[(size_t)b * NGT + tid] < BGCLS;
    }
    unsigned long long m = __ballot(valid);
    int w = tid >> 6;
    if ((tid & 63) == 0) wtmp[w] = __popcll(m);
    __syncthreads();
    if (tid == 0) snv = wtmp[0] + wtmp[1] + wtmp[2] + wtmp[3];
    if (valid) {
      int off = 0;
      for (int i = 0; i < w; ++i) off += wtmp[i];
      int pos = off + __popcll(m & ((1ull << (tid & 63)) - 1ull));
      cbox[pos] = p;
      carea[pos] = (p.z - p.x) * (p.w - p.y);
    }
    __syncthreads();
  }
  const int nv = snv;
  const int n0 = blockIdx.x * IOBLK + tid;

  float4 rb[RPT]; float ar[RPT]; float v1[RPT], v2[RPT]; int j1[RPT];
#pragma unroll
  for (int k = 0; k < RPT; ++k) {
    int n = n0 + (k << 8);
    rb[k] = (n < NROI) ? *(const float4*)(rois + ((size_t)b * NROI + n) * 4)
                       : make_float4(2.f, 2.f, 2.f, 2.f);
    ar[k] = (rb[k].z - rb[k].x) * (rb[k].w - rb[k].y);
    v1[k] = -1.0f; v2[k] = -2.0f; j1[k] = 0;
  }
#pragma unroll 2
  for (int j = 0; j < nv; ++j) {                 // uniform loop, no divergence
    float4 q = cbox[j];
    float ag = carea[j];
#pragma unroll
    for (int k = 0; k < RPT; ++k) {
      float yy1 = fmaxf(rb[k].x, q.x);
      float xx1 = fmaxf(rb[k].y, q.y);
      float yy2 = fminf(rb[k].z, q.z);
      float xx2 = fminf(rb[k].w, q.w);
      float inter = fmaxf(yy2 - yy1, 0.0f) * fmaxf(xx2 - xx1, 0.0f);
      float den = ((ar[k] + ag) - inter) + 1e-8f;
      float a = inter * __builtin_amdgcn_rcpf(den);
      bool gt = a > v1[k];                       // strict > : ties keep first j
      v2[k] = gt ? v1[k] : fmaxf(v2[k], a);      // second-best approx
      j1[k] = gt ? j : j1[k];
      v1[k] = gt ? a : v1[k];
    }
  }
#pragma unroll
  for (int k = 0; k < RPT; ++k) {
    int n = n0 + (k << 8);
    if (n >= NROI) continue;
    float best; int bj;
    if (nv == 0) {
      best = -1.0f; bj = 0;                      // never occurs for this data
    } else if (v2[k] >= v1[k] * 0.999995f) {     // near-tie -> exact fallback
      roi_maxiou_all(cbox, carea, nv, rb[k].x, rb[k].y, rb[k].z, rb[k].w, best, bj);
    } else {                                     // unique winner: exact value
      float4 q = cbox[j1[k]];
      float yy1 = fmaxf(rb[k].x, q.x);
      float xx1 = fmaxf(rb[k].y, q.y);
      float yy2 = fminf(rb[k].z, q.z);
      float xx2 = fminf(rb[k].w, q.w);
      float inter = fmaxf(yy2 - yy1, 0.0f) * fmaxf(xx2 - xx1, 0.0f);
      float den = ((ar[k] + carea[j1[k]]) - inter) + 1e-8f;
      best = inter / den;                        // IEEE f32 div, bit-exact
      bj = j1[k];
    }
    max_iou[(size_t)b * NROI + n] = best;
    best_j[(size_t)b * NROI + n] = bj;
  }
}

// One 1024-thread block per image. Two top-k phases (pos v>=0.5 by bits(v);
// neg 0<=v<0.5 by bits(f32(v+2.0)) -- the +2.0 ROUNDING merges nearby ious,
// merged ties break asc-index). key = kh<<32 | (0x7fffffff-n): desc ==
// (val desc, idx asc) == jax stable top_k. max_iou register-resident
// (12/thread); histogram-prune (lane-sharded, wave-shuffle suffix scan) +
// ballot-compacted candidates + rank selection (keys unique).
template <bool USE_WS>
__global__ __launch_bounds__(TSEL) void k_sel(const float* __restrict__ rois,
                                              const int* __restrict__ gtc,
                                              const float* __restrict__ gtb,
                                              const float* __restrict__ max_iou,
                                              const int* __restrict__ best_j,
                                              float* __restrict__ out) {
#pragma clang fp contract(off)
  __shared__ float4 cbox[NGT];
  __shared__ float carea[NGT];
  __shared__ int ccls[NGT];
  __shared__ int snv, wtmp[16];
  __shared__ int wtot[16], wnext[16];
  __shared__ unsigned long long list[CAP];
  __shared__ int hs[HSH][HST];
  __shared__ int ss[NBIN];
  __shared__ int sel_r[ROIBS];
  __shared__ int scnt, sT;
  const int b = blockIdx.x;
  const int tid = threadIdx.x;
  const int lane = tid & 63;

  {                                              // order-preserving compaction
    bool valid = false; float4 p = make_float4(0.f, 0.f, 0.f, 0.f); int cls = BGCLS;
    if (tid < NGT) {
      p = *(const float4*)(gtb + ((size_t)b * NGT + tid) * 4);
      cls = gtc[(size_t)b * NGT + tid];
      valid = (cls < BGCLS);
    }
    unsigned long long m = __ballot(valid);
    int w = tid >> 6;
    if ((tid & 63) == 0) wtmp[w] = __popcll(m);
    if (tid < ROIBS) sel_r[tid] = 0;             // default roi (slot underflow)
    __syncthreads();
    if (tid == 0) { int s = 0; for (int i = 0; i < 16; ++i) s += wtmp[i]; snv = s; }
    if (valid) {
      int off = 0;
      for (int i = 0; i < w; ++i) off += wtmp[i];
      int pos = off + __popcll(m & ((1ull << (tid & 63)) - 1ull));
      cbox[pos] = p;
      carea[pos] = (p.z - p.x) * (p.w - p.y);
      ccls[pos] = cls;
    }
    __syncthreads();
  }
  const int nv = snv;

  // ---- register-resident max_iou: n = tid + i*1024 (static indexing) ----
  float v[VPT2];
#pragma unroll
  for (int i = 0; i < VPT2; ++i) {
    int n = tid + (i << 10);
    if constexpr (USE_WS) {
      v[i] = (n < NROI) ? max_iou[(size_t)b * NROI + n] : -3.0f;
    } else {
      if (n < NROI) {
        const float4 r = *(const float4*)(rois + ((size_t)b * NROI + n) * 4);
        float best; int bj;
        roi_maxiou_all(cbox, carea, nv, r.x, r.y, r.z, r.w, best, bj);
        v[i] = best;
      } else v[i] = -3.0f;
    }
  }

  // One phase: filter [lo,hi), key kh = bits(isPos ? v : v+2.0f), bin
  // monotone in key (equal keys -> equal bin). T = highest bin with
  // suffix >= need; candidates (bin>=T) ranked desc -> slots. Returns #filled.
  auto phase = [&](bool isPos, int need, unsigned base, int shift,
                   float lo, float hi, int slotBase) -> int {
    for (int i = tid; i < HSH * HST; i += TSEL) ((int*)hs)[i] = 0;
    if (tid == 0) { scnt = 0; sT = 0; }
    __syncthreads();
    const int sh = tid & (HSH - 1);              // lane-based: same bin ->
#pragma unroll                                   // 16 banks, 16 addresses
    for (int i = 0; i < VPT2; ++i) {
      float x = v[i];
      if (x >= lo && x < hi) {
        float kv = isPos ? x : (x + 2.0f);       // IEEE RNE, no contraction
        int bin = min((int)((__float_as_uint(kv) - base) >> shift), NBIN - 1);
        atomicAdd(&hs[sh][bin], 1);
      }
    }
    __syncthreads();
    // suffix scan over 1024 bins: wave shuffle scan + 16-wave combine
    int cnt_bin = 0;
#pragma unroll
    for (int i = 0; i < HSH; ++i) cnt_bin += hs[i][tid];
    const int w = tid >> 6;
    int sfx = cnt_bin;                           // per-wave suffix (bins desc)
#pragma unroll
    for (int off = 1; off < 64; off <<= 1) {
      int t = __shfl_down(sfx, off, 64);
      sfx += (lane + off < 64) ? t : 0;
    }
    if (lane == 0) wtot[w] = sfx;                // wave total
    __syncthreads();
    if (tid < 16) {
      int s = 0;
      for (int i = tid + 1; i < 16; ++i) s += wtot[i];
      wnext[tid] = s;                            // sum over waves after w
    }
    __syncthreads();
    const int suffix = sfx + wnext[w];           // total over bins >= tid
    ss[tid] = suffix;
    __syncthreads();
    {
      int nxt = (tid + 1 < NBIN) ? ss[tid + 1] : 0;
      if (suffix >= need && nxt < need) sT = tid;
    }
    __syncthreads();
    const int T = sT;                            // 0 if total < need (take all)
#pragma unroll
    for (int i = 0; i < VPT2; ++i) {             // ballot-compacted candidates
      int n = tid + (i << 10);
      float x = v[i];
      bool pred = (x >= lo && x < hi);
      unsigned kh = 0; 
      if (pred) {
        kh = __float_as_uint(isPos ? x : (x + 2.0f));
        int bin = min((int)((kh - base) >> shift), NBIN - 1);
        pred = (bin >= T);
      }
      unsigned long long mk = __ballot(pred);
      int c = __popcll(mk);
      int bs = 0;
      if (lane == 0 && c) bs = atomicAdd(&scnt, c);
      bs = __shfl(bs, 0, 64);
      if (pred) {
        int idx = bs + __popcll(mk & ((1ull << lane) - 1ull));
        if (idx < CAP)
          list[idx] = ((unsigned long long)kh << 32) | (unsigned)(0x7fffffff - n);
      }
    }
    __syncthreads();
    const int cnt = min(scnt, CAP);
    const int limit = min(cnt, need);
    if (tid < cnt) {                             // rank selection, keys unique
      unsigned long long ki = list[tid];
      int rank = 0;
      for (int j = 0; j < cnt; ++j) rank += (list[j] > ki);  // LDS broadcast
      if (rank < limit)
        sel_r[slotBase + rank] = 0x7fffffff - (int)(ki & 0xffffffffu);
    }
    __syncthreads();
    return limit;
  };

  // positives: top-64 of v >= 0.5; emission == pick order (f32 prio 1e9-rP
  // tie-collapse + stable top_k keeps slot order). negatives fill P..255.
  const int P = phase(true, NPOS, 0x3F000000u, 13, 0.5f, 3.0f, 0);
  phase(false, ROIBS - P, 0x40000000u, 11, 0.0f, 0.5f, P);

  // ===== emit (f32 output): 4 threads per slot; covers all of d_out =====
  {
    const int slot = tid >> 2, q = tid & 3;
    const int r = sel_r[slot];
    const int isp = (slot < P) ? 1 : 0;
    const float4 rv = *(const float4*)(rois + ((size_t)b * NROI + r) * 4);
    float ry1 = rv.x, rx1 = rv.y, ry2 = rv.z, rx2 = rv.w;
    int bj;
    if constexpr (USE_WS) {
      bj = best_j[(size_t)b * NROI + r];
    } else {
      float bb;
      roi_maxiou_all(cbox, carea, nv, ry1, rx1, ry2, rx2, bb, bj);
    }
    int label = isp ? ccls[bj] : BGCLS;

    float* out1 = out;                                    // [B,256,4]
    float* out2 = out + (size_t)BATCH * ROIBS * 4;        // [B,256,21]
    float* out3 = out + (size_t)BATCH * ROIBS * 25;       // [B,256,160]
    size_t row = (size_t)b * ROIBS + slot;

    if (q == 0) {
      *(float4*)(out1 + row * 4) = rv;                    // bit-exact roi copy
      float* o2 = out2 + row * 21;
      for (int c = 0; c <= BGCLS; ++c) o2[c] = (c == label) ? 1.0f : 0.0f;
    }

    float t0 = 0.f, t1 = 0.f, t2 = 0.f, t3 = 0.f;
    if (isp) {
      const float eps = 1e-6f;
      float4 g = cbox[bj];
      float gy1 = g.x, gx1 = g.y, gy2 = g.z, gx2 = g.w;
      float rh = ry2 - ry1, rw = rx2 - rx1;
      float rcy = ry1 + rh * 0.5f, rcx = rx1 + rw * 0.5f;
      float gh = gy2 - gy1, gw = gx2 - gx1;
      float gcy = gy1 + gh * 0.5f, gcx = gx1 + gw * 0.5f;
      t0 = ((gcx - rcx) / (rw + eps)) * 10.0f;
      t1 = ((gcy - rcy) / (rh + eps)) * 10.0f;
      t2 = logf(fmaxf(gw, eps) / (rw + eps)) * 5.0f;
      t3 = logf(fmaxf(gh, eps) / (rh + eps)) * 5.0f;
    }
    int m0 = label * 4;                          // meaningful only when isp
    float* o3 = out3 + row * 160;
    for (int c = q * 10; c < q * 10 + 10; ++c) { // 10 x 16B stores per thread
      float4 wv = make_float4(0.f, 0.f, 0.f, 0.f);
      if (isp) {
        float* wp = &wv.x;
#pragma unroll
        for (int jj = 0; jj < 4; ++jj) {
          int e = c * 4 + jj;
          float x = 0.f;
          if (e >= m0 && e < m0 + 4) x = 1.0f;   // mask4 half [0,80)
          int d = e - 80 - m0;                   // deltas half [80,160)
          if (d == 0) x = t0; else if (d == 1) x = t1;
          else if (d == 2) x = t2; else if (d == 3) x = t3;
          wp[jj] = x;
        }
      }
      *(float4*)(o3 + c * 4) = wv;
    }
  }
}

extern "C" void kernel_launch(void* const* d_in, const int* in_sizes, int n_in,
                              void* d_out, int out_size, void* d_ws, size_t ws_size,
                              hipStream_t stream) {
  const float* rois = (const float*)d_in[0];   // [32,12000,4] f32
  const int*   gtc  = (const int*)d_in[1];     // [32,200] i32
  const float* gtb  = (const float*)d_in[2];   // [32,200,4] f32
  float*       out  = (float*)d_out;           // f32, 32*256*185 elements

  size_t need = (size_t)BATCH * NROI * 8;      // f32 max_iou + i32 best_j
  if (d_ws && ws_size >= need) {
    float* mi = (float*)d_ws;
    int*   bj = (int*)d_ws + (size_t)BATCH * NROI;
    k_ioumax<<<dim3((NROI + IOBLK - 1) / IOBLK, BATCH), 256, 0, stream>>>(rois, gtc, gtb, mi, bj);
    k_sel<true><<<BATCH, TSEL, 0, stream>>>(rois, gtc, gtb, mi, bj, out);
  } else {
    k_sel<false><<<BATCH, TSEL, 0, stream>>>(rois, gtc, gtb, nullptr, nullptr, out);
  }
}